// Round 1
// baseline (397.799 us; speedup 1.0000x reference)
//
#include <hip/hip_runtime.h>
#include <stdint.h>

#define TOK 8192      // B*S
#define DIM 1024
#define NE 8

typedef short bf16x8 __attribute__((ext_vector_type(8)));
typedef float f32x4 __attribute__((ext_vector_type(4)));

__device__ __forceinline__ unsigned short f2bf(float f) {
  unsigned int u = __float_as_uint(f);
  u += 0x7FFFu + ((u >> 16) & 1u);
  return (unsigned short)(u >> 16);
}

__device__ __forceinline__ void gl_lds16(const void* g, void* l) {
  __builtin_amdgcn_global_load_lds(
      (__attribute__((address_space(1))) unsigned int*)(g),
      (__attribute__((address_space(3))) unsigned int*)(l), 16, 0, 0);
}

__global__ void zero_cnt(int* cnt) {
  if (threadIdx.x < NE) cnt[threadIdx.x] = 0;
}

// One wave per token: convert x row to bf16 + gating dots (fp64 acc) + top-2 push.
__global__ __launch_bounds__(256) void gate_kernel(
    const float* __restrict__ x, const float* __restrict__ gW,
    const float* __restrict__ gb, unsigned short* __restrict__ xb,
    int* __restrict__ cnt, int* __restrict__ listTok, float* __restrict__ listW)
{
  const int wave = threadIdx.x >> 6;
  const int lane = threadIdx.x & 63;
  const int t = blockIdx.x * 4 + wave;
  const float4* xrow = (const float4*)(x + (size_t)t * DIM);
  ushort4* xbrow = (ushort4*)(xb + (size_t)t * DIM);

  double acc[NE];
#pragma unroll
  for (int e = 0; e < NE; ++e) acc[e] = 0.0;

#pragma unroll
  for (int i = 0; i < 4; ++i) {
    const int j = i * 64 + lane;         // float4 index within row (0..255)
    float4 v = xrow[j];
    ushort4 pk;
    pk.x = f2bf(v.x); pk.y = f2bf(v.y); pk.z = f2bf(v.z); pk.w = f2bf(v.w);
    xbrow[j] = pk;
    const float* g = gW + (size_t)j * 4 * NE;
    float xv[4] = {v.x, v.y, v.z, v.w};
#pragma unroll
    for (int c = 0; c < 4; ++c) {
#pragma unroll
      for (int e = 0; e < NE; ++e)
        acc[e] += (double)xv[c] * (double)g[c * NE + e];
    }
  }
  // wave64 butterfly reduce (doubles)
#pragma unroll
  for (int off = 32; off > 0; off >>= 1) {
#pragma unroll
    for (int e = 0; e < NE; ++e)
      acc[e] += __shfl_xor(acc[e], off, 64);
  }

  if (lane == 0) {
    double s[NE];
#pragma unroll
    for (int e = 0; e < NE; ++e) {
      s[e] = acc[e] + (double)gb[e];
      if (s[e] < 1e-4) s[e] = 1e-4;     // clamp-min(EPS), TEMP=1
    }
    double m = s[0];
    for (int e = 1; e < NE; ++e) if (s[e] > m) m = s[e];
    double p[NE], Z = 0.0;
    for (int e = 0; e < NE; ++e) { p[e] = exp(s[e] - m); Z += p[e]; }
    // top-2 by value, ties -> lower index (strict > scan)
    int e0 = 0;
    for (int e = 1; e < NE; ++e) if (s[e] > s[e0]) e0 = e;
    int e1 = (e0 == 0) ? 1 : 0;
    for (int e = 0; e < NE; ++e) if (e != e0 && s[e] > s[e1]) e1 = e;
    double w0 = p[e0] / Z; if (w0 < 0.1) w0 = 0.1;
    double w1 = p[e1] / Z; if (w1 < 0.1) w1 = 0.1;
    const double inv = 0.5 / (w0 + w1);   // /total /K
    int p0 = atomicAdd(&cnt[e0], 1);
    listTok[e0 * TOK + p0] = t * 2 + 0;   // token*2 + slot
    listW [e0 * TOK + p0] = (float)(w0 * inv);
    int p1 = atomicAdd(&cnt[e1], 1);
    listTok[e1 * TOK + p1] = t * 2 + 1;
    listW [e1 * TOK + p1] = (float)(w1 * inv);
  }
}

// expert_W [e][d][f] fp32 -> Wt [e][f][d] bf16 (32x32 LDS tile transpose)
__global__ __launch_bounds__(256) void transpose_w(
    const float* __restrict__ W, unsigned short* __restrict__ Wt)
{
  __shared__ float tile[32][33];
  const int e = blockIdx.z;
  const int d0 = blockIdx.y * 32, f0 = blockIdx.x * 32;
  const int tx = threadIdx.x & 31, ty = threadIdx.x >> 5;
  const float* src = W + ((size_t)e * DIM + d0) * DIM + f0;
#pragma unroll
  for (int r = ty; r < 32; r += 8)
    tile[r][tx] = src[(size_t)r * DIM + tx];
  __syncthreads();
  unsigned short* dst = Wt + ((size_t)e * DIM + f0) * DIM + d0;
#pragma unroll
  for (int r = ty; r < 32; r += 8)
    dst[(size_t)r * DIM + tx] = f2bf(tile[tx][r]);
}

// tiles[0]=n; then per row-tile: {expert, row_start, rows}
__global__ void build_desc(const int* __restrict__ cnt, int* __restrict__ tiles)
{
  if (threadIdx.x == 0 && blockIdx.x == 0) {
    int n = 0;
    for (int e = 0; e < NE; ++e) {
      int c = cnt[e];
      for (int r = 0; r < c; r += 128) {
        tiles[1 + n * 3] = e;
        tiles[2 + n * 3] = r;
        tiles[3 + n * 3] = (c - r < 128) ? (c - r) : 128;
        ++n;
      }
    }
    tiles[0] = n;   // <= 136
  }
}

// Grouped GEMM: 128(tokens) x 128(f) tile, BK=32, 16x16x32 bf16 MFMA.
__global__ __launch_bounds__(256) void moe_gemm(
    const unsigned short* __restrict__ xb, const unsigned short* __restrict__ Wt,
    const float* __restrict__ eb, const int* __restrict__ tiles,
    const int* __restrict__ listTok, const float* __restrict__ listW,
    float* __restrict__ yslot)
{
  const int dId = blockIdx.x >> 3;
  const int cT  = blockIdx.x & 7;
  if (dId >= tiles[0]) return;
  const int e    = tiles[1 + dId * 3];
  const int r0   = tiles[2 + dId * 3];
  const int rows = tiles[3 + dId * 3];

  __shared__ __align__(16) unsigned short As[128 * 32];  // rows=tokens, stride 32
  __shared__ __align__(16) unsigned short Bs[128 * 32];  // rows=f,      stride 32
  __shared__ int   tid_s[128];
  __shared__ float w_s[128];

  const int tid = threadIdx.x;
  if (tid < 128) {
    if (tid < rows) {
      tid_s[tid] = listTok[e * TOK + r0 + tid];
      w_s[tid]   = listW [e * TOK + r0 + tid];
    } else {
      tid_s[tid] = 0;     // safe dummy row (token 0) — never stored
      w_s[tid]   = 0.0f;
    }
  }
  __syncthreads();

  const int w    = tid >> 6;
  const int lane = tid & 63;
  const int kq   = lane & 3;                 // 16B quarter within 64B row
  const int rA0  = w * 32 + (lane >> 2);     // staging row, issue 0
  const int rA1  = rA0 + 16;                 // staging row, issue 1
  const unsigned short* srcA0 = xb + (size_t)(tid_s[rA0] >> 1) * DIM + kq * 8;
  const unsigned short* srcA1 = xb + (size_t)(tid_s[rA1] >> 1) * DIM + kq * 8;
  const unsigned short* srcB0 = Wt + ((size_t)e * DIM + cT * 128 + rA0) * DIM + kq * 8;
  const unsigned short* srcB1 = Wt + ((size_t)e * DIM + cT * 128 + rA1) * DIM + kq * 8;
  unsigned short* ldsA = &As[w * 1024];      // wave-uniform bases (+ lane*16B implicit)
  unsigned short* ldsB = &Bs[w * 1024];

  const int wr = w >> 1, wc = w & 1;
  const int mrow = lane & 15;
  const int koff = (lane >> 4) * 8;

  f32x4 acc[4][4];
#pragma unroll
  for (int i = 0; i < 4; ++i)
#pragma unroll
    for (int j = 0; j < 4; ++j)
      acc[i][j] = {0.f, 0.f, 0.f, 0.f};

  for (int kc = 0; kc < DIM / 32; ++kc) {
    const int k0 = kc * 32;
    __syncthreads();                         // prev iter's frag reads done
    gl_lds16(srcA0 + k0, ldsA);
    gl_lds16(srcA1 + k0, ldsA + 512);
    gl_lds16(srcB0 + k0, ldsB);
    gl_lds16(srcB1 + k0, ldsB + 512);
    __syncthreads();                         // vmcnt(0) drain => LDS ready
    bf16x8 af[4], bfr[4];
#pragma unroll
    for (int mt = 0; mt < 4; ++mt)
      af[mt] = *(const bf16x8*)&As[(wr * 64 + mt * 16 + mrow) * 32 + koff];
#pragma unroll
    for (int nt = 0; nt < 4; ++nt)
      bfr[nt] = *(const bf16x8*)&Bs[(wc * 64 + nt * 16 + mrow) * 32 + koff];
#pragma unroll
    for (int mt = 0; mt < 4; ++mt)
#pragma unroll
      for (int nt = 0; nt < 4; ++nt)
        acc[mt][nt] = __builtin_amdgcn_mfma_f32_16x16x32_bf16(
            af[mt], bfr[nt], acc[mt][nt], 0, 0, 0);
  }

  // epilogue: C/D map col=lane&15, row=(lane>>4)*4+r
  const int colBase = cT * 128 + wc * 64 + mrow;
  float bias[4];
#pragma unroll
  for (int nt = 0; nt < 4; ++nt)
    bias[nt] = eb[(size_t)e * DIM + colBase + nt * 16];
#pragma unroll
  for (int mt = 0; mt < 4; ++mt) {
#pragma unroll
    for (int r = 0; r < 4; ++r) {
      const int rloc = wr * 64 + mt * 16 + (lane >> 4) * 4 + r;
      if (rloc < rows) {
        const int tk    = tid_s[rloc];
        const float wgt = w_s[rloc];
        float* dst = yslot + ((size_t)(tk & 1) * TOK + (size_t)(tk >> 1)) * DIM;
#pragma unroll
        for (int nt = 0; nt < 4; ++nt)
          dst[colBase + nt * 16] = wgt * (acc[mt][nt][r] + bias[nt]);
      }
    }
  }
}

__global__ __launch_bounds__(256) void combine(
    const float4* __restrict__ y0, const float4* __restrict__ y1,
    float4* __restrict__ out)
{
  const size_t i = (size_t)blockIdx.x * 256 + threadIdx.x;
  float4 a = y0[i], b = y1[i];
  float4 o;
  o.x = a.x + b.x; o.y = a.y + b.y; o.z = a.z + b.z; o.w = a.w + b.w;
  out[i] = o;
}

extern "C" void kernel_launch(void* const* d_in, const int* in_sizes, int n_in,
                              void* d_out, int out_size, void* d_ws, size_t ws_size,
                              hipStream_t stream)
{
  const float* x  = (const float*)d_in[0];
  const float* gW = (const float*)d_in[1];
  const float* gb = (const float*)d_in[2];
  const float* eW = (const float*)d_in[3];
  const float* eb = (const float*)d_in[4];
  float* out = (float*)d_out;

  char* p = (char*)d_ws;
  unsigned short* xb = (unsigned short*)p;  p += (size_t)TOK * DIM * 2;       // 16 MB
  unsigned short* Wt = (unsigned short*)p;  p += (size_t)NE * DIM * DIM * 2;  // 16 MB
  float* yslot = (float*)p;                 p += (size_t)2 * TOK * DIM * 4;   // 64 MB
  int* cnt = (int*)p;                       p += 256;
  int* listTok = (int*)p;                   p += (size_t)NE * TOK * 4;
  float* listW = (float*)p;                 p += (size_t)NE * TOK * 4;
  int* tiles = (int*)p;                     p += 4096;

  zero_cnt<<<1, 64, 0, stream>>>(cnt);
  gate_kernel<<<TOK / 4, 256, 0, stream>>>(x, gW, gb, xb, cnt, listTok, listW);
  transpose_w<<<dim3(32, 32, 8), 256, 0, stream>>>(eW, Wt);
  build_desc<<<1, 64, 0, stream>>>(cnt, tiles);
  moe_gemm<<<136 * 8, 256, 0, stream>>>(xb, Wt, eb, tiles, listTok, listW, yslot);
  combine<<<TOK * DIM / 4 / 256, 256, 0, stream>>>(
      (const float4*)yslot, (const float4*)yslot + (size_t)TOK * DIM / 4, (float4*)out);
}

// Round 2
// 235.970 us; speedup vs baseline: 1.6858x; 1.6858x over previous
//
#include <hip/hip_runtime.h>
#include <stdint.h>

#define TOK 8192      // B*S
#define DIM 1024
#define NE 8

typedef short bf16x8 __attribute__((ext_vector_type(8)));
typedef float f32x4 __attribute__((ext_vector_type(4)));

__device__ __forceinline__ unsigned short f2bf(float f) {
  unsigned int u = __float_as_uint(f);
  u += 0x7FFFu + ((u >> 16) & 1u);
  return (unsigned short)(u >> 16);
}

__device__ __forceinline__ void gl_lds16(const void* g, void* l) {
  __builtin_amdgcn_global_load_lds(
      (__attribute__((address_space(1))) unsigned int*)(g),
      (__attribute__((address_space(3))) unsigned int*)(l), 16, 0, 0);
}

__global__ void zero_cnt(int* cnt) {
  if (threadIdx.x < NE) cnt[threadIdx.x] = 0;
}

// One wave per token: convert x row to bf16 + gating dots (fp64 acc) + write picks.
// NO global atomics here (R1 post-mortem: 16384 same-line fetch-adds = 207 us serial).
__global__ __launch_bounds__(256) void gate_kernel(
    const float* __restrict__ x, const float* __restrict__ gW,
    const float* __restrict__ gb, unsigned short* __restrict__ xb,
    int* __restrict__ eSel, float* __restrict__ wSel)
{
  const int wave = threadIdx.x >> 6;
  const int lane = threadIdx.x & 63;
  const int t = blockIdx.x * 4 + wave;
  const float4* xrow = (const float4*)(x + (size_t)t * DIM);
  ushort4* xbrow = (ushort4*)(xb + (size_t)t * DIM);

  double acc[NE];
#pragma unroll
  for (int e = 0; e < NE; ++e) acc[e] = 0.0;

#pragma unroll
  for (int i = 0; i < 4; ++i) {
    const int j = i * 64 + lane;         // float4 index within row (0..255)
    float4 v = xrow[j];
    ushort4 pk;
    pk.x = f2bf(v.x); pk.y = f2bf(v.y); pk.z = f2bf(v.z); pk.w = f2bf(v.w);
    xbrow[j] = pk;
    const float* g = gW + (size_t)j * 4 * NE;
    float xv[4] = {v.x, v.y, v.z, v.w};
#pragma unroll
    for (int c = 0; c < 4; ++c) {
#pragma unroll
      for (int e = 0; e < NE; ++e)
        acc[e] += (double)xv[c] * (double)g[c * NE + e];
    }
  }
  // wave64 butterfly reduce (doubles)
#pragma unroll
  for (int off = 32; off > 0; off >>= 1) {
#pragma unroll
    for (int e = 0; e < NE; ++e)
      acc[e] += __shfl_xor(acc[e], off, 64);
  }

  if (lane == 0) {
    double s[NE];
#pragma unroll
    for (int e = 0; e < NE; ++e) {
      s[e] = acc[e] + (double)gb[e];
      if (s[e] < 1e-4) s[e] = 1e-4;     // clamp-min(EPS), TEMP=1
    }
    double m = s[0];
    for (int e = 1; e < NE; ++e) if (s[e] > m) m = s[e];
    double p[NE], Z = 0.0;
    for (int e = 0; e < NE; ++e) { p[e] = exp(s[e] - m); Z += p[e]; }
    // top-2 by value, ties -> lower index (strict > scan)
    int e0 = 0;
    for (int e = 1; e < NE; ++e) if (s[e] > s[e0]) e0 = e;
    int e1 = (e0 == 0) ? 1 : 0;
    for (int e = 0; e < NE; ++e) if (e != e0 && s[e] > s[e1]) e1 = e;
    double w0 = p[e0] / Z; if (w0 < 0.1) w0 = 0.1;
    double w1 = p[e1] / Z; if (w1 < 0.1) w1 = 0.1;
    const double inv = 0.5 / (w0 + w1);   // /total /K
    eSel[t * 2 + 0] = e0;
    eSel[t * 2 + 1] = e1;
    wSel[t * 2 + 0] = (float)(w0 * inv);
    wSel[t * 2 + 1] = (float)(w1 * inv);
  }
}

// Two-level scatter: LDS histogram per block (256 tokens), 8 global atomics per
// block for base offsets, then conflict-free placement. 256 global atomics total.
__global__ __launch_bounds__(256) void scatter_kernel(
    const int* __restrict__ eSel, const float* __restrict__ wSel,
    int* __restrict__ cnt, int* __restrict__ listTok, float* __restrict__ listW)
{
  __shared__ int lcnt[NE];
  __shared__ int base[NE];
  const int tid = threadIdx.x;
  if (tid < NE) lcnt[tid] = 0;
  __syncthreads();

  const int t = blockIdx.x * 256 + tid;
  const int e0 = eSel[t * 2 + 0];
  const int e1 = eSel[t * 2 + 1];
  const float w0 = wSel[t * 2 + 0];
  const float w1 = wSel[t * 2 + 1];
  const int l0 = atomicAdd(&lcnt[e0], 1);
  const int l1 = atomicAdd(&lcnt[e1], 1);
  __syncthreads();
  if (tid < NE) base[tid] = atomicAdd(&cnt[tid], lcnt[tid]);
  __syncthreads();

  const int p0 = base[e0] + l0;
  listTok[e0 * TOK + p0] = t * 2 + 0;   // token*2 + slot
  listW [e0 * TOK + p0] = w0;
  const int p1 = base[e1] + l1;
  listTok[e1 * TOK + p1] = t * 2 + 1;
  listW [e1 * TOK + p1] = w1;
}

// expert_W [e][d][f] fp32 -> Wt [e][f][d] bf16 (32x32 LDS tile transpose)
__global__ __launch_bounds__(256) void transpose_w(
    const float* __restrict__ W, unsigned short* __restrict__ Wt)
{
  __shared__ float tile[32][33];
  const int e = blockIdx.z;
  const int d0 = blockIdx.y * 32, f0 = blockIdx.x * 32;
  const int tx = threadIdx.x & 31, ty = threadIdx.x >> 5;
  const float* src = W + ((size_t)e * DIM + d0) * DIM + f0;
#pragma unroll
  for (int r = ty; r < 32; r += 8)
    tile[r][tx] = src[(size_t)r * DIM + tx];
  __syncthreads();
  unsigned short* dst = Wt + ((size_t)e * DIM + f0) * DIM + d0;
#pragma unroll
  for (int r = ty; r < 32; r += 8)
    dst[(size_t)r * DIM + tx] = f2bf(tile[tx][r]);
}

// tiles[0]=n; then per row-tile: {expert, row_start, rows}
__global__ void build_desc(const int* __restrict__ cnt, int* __restrict__ tiles)
{
  if (threadIdx.x == 0 && blockIdx.x == 0) {
    int n = 0;
    for (int e = 0; e < NE; ++e) {
      int c = cnt[e];
      for (int r = 0; r < c; r += 128) {
        tiles[1 + n * 3] = e;
        tiles[2 + n * 3] = r;
        tiles[3 + n * 3] = (c - r < 128) ? (c - r) : 128;
        ++n;
      }
    }
    tiles[0] = n;   // <= 136
  }
}

// Grouped GEMM: 128(tokens) x 128(f) tile, BK=32, 16x16x32 bf16 MFMA.
__global__ __launch_bounds__(256) void moe_gemm(
    const unsigned short* __restrict__ xb, const unsigned short* __restrict__ Wt,
    const float* __restrict__ eb, const int* __restrict__ tiles,
    const int* __restrict__ listTok, const float* __restrict__ listW,
    float* __restrict__ yslot)
{
  const int dId = blockIdx.x >> 3;
  const int cT  = blockIdx.x & 7;
  if (dId >= tiles[0]) return;
  const int e    = tiles[1 + dId * 3];
  const int r0   = tiles[2 + dId * 3];
  const int rows = tiles[3 + dId * 3];

  __shared__ __align__(16) unsigned short As[128 * 32];  // rows=tokens, stride 32
  __shared__ __align__(16) unsigned short Bs[128 * 32];  // rows=f,      stride 32
  __shared__ int   tid_s[128];
  __shared__ float w_s[128];

  const int tid = threadIdx.x;
  if (tid < 128) {
    if (tid < rows) {
      tid_s[tid] = listTok[e * TOK + r0 + tid];
      w_s[tid]   = listW [e * TOK + r0 + tid];
    } else {
      tid_s[tid] = 0;     // safe dummy row (token 0) — never stored
      w_s[tid]   = 0.0f;
    }
  }
  __syncthreads();

  const int w    = tid >> 6;
  const int lane = tid & 63;
  const int kq   = lane & 3;                 // 16B quarter within 64B row
  const int rA0  = w * 32 + (lane >> 2);     // staging row, issue 0
  const int rA1  = rA0 + 16;                 // staging row, issue 1
  const unsigned short* srcA0 = xb + (size_t)(tid_s[rA0] >> 1) * DIM + kq * 8;
  const unsigned short* srcA1 = xb + (size_t)(tid_s[rA1] >> 1) * DIM + kq * 8;
  const unsigned short* srcB0 = Wt + ((size_t)e * DIM + cT * 128 + rA0) * DIM + kq * 8;
  const unsigned short* srcB1 = Wt + ((size_t)e * DIM + cT * 128 + rA1) * DIM + kq * 8;
  unsigned short* ldsA = &As[w * 1024];      // wave-uniform bases (+ lane*16B implicit)
  unsigned short* ldsB = &Bs[w * 1024];

  const int wr = w >> 1, wc = w & 1;
  const int mrow = lane & 15;
  const int koff = (lane >> 4) * 8;

  f32x4 acc[4][4];
#pragma unroll
  for (int i = 0; i < 4; ++i)
#pragma unroll
    for (int j = 0; j < 4; ++j)
      acc[i][j] = {0.f, 0.f, 0.f, 0.f};

  for (int kc = 0; kc < DIM / 32; ++kc) {
    const int k0 = kc * 32;
    __syncthreads();                         // prev iter's frag reads done
    gl_lds16(srcA0 + k0, ldsA);
    gl_lds16(srcA1 + k0, ldsA + 512);
    gl_lds16(srcB0 + k0, ldsB);
    gl_lds16(srcB1 + k0, ldsB + 512);
    __syncthreads();                         // vmcnt(0) drain => LDS ready
    bf16x8 af[4], bfr[4];
#pragma unroll
    for (int mt = 0; mt < 4; ++mt)
      af[mt] = *(const bf16x8*)&As[(wr * 64 + mt * 16 + mrow) * 32 + koff];
#pragma unroll
    for (int nt = 0; nt < 4; ++nt)
      bfr[nt] = *(const bf16x8*)&Bs[(wc * 64 + nt * 16 + mrow) * 32 + koff];
#pragma unroll
    for (int mt = 0; mt < 4; ++mt)
#pragma unroll
      for (int nt = 0; nt < 4; ++nt)
        acc[mt][nt] = __builtin_amdgcn_mfma_f32_16x16x32_bf16(
            af[mt], bfr[nt], acc[mt][nt], 0, 0, 0);
  }

  // epilogue: C/D map col=lane&15, row=(lane>>4)*4+r
  const int colBase = cT * 128 + wc * 64 + mrow;
  float bias[4];
#pragma unroll
  for (int nt = 0; nt < 4; ++nt)
    bias[nt] = eb[(size_t)e * DIM + colBase + nt * 16];
#pragma unroll
  for (int mt = 0; mt < 4; ++mt) {
#pragma unroll
    for (int r = 0; r < 4; ++r) {
      const int rloc = wr * 64 + mt * 16 + (lane >> 4) * 4 + r;
      if (rloc < rows) {
        const int tk    = tid_s[rloc];
        const float wgt = w_s[rloc];
        float* dst = yslot + ((size_t)(tk & 1) * TOK + (size_t)(tk >> 1)) * DIM;
#pragma unroll
        for (int nt = 0; nt < 4; ++nt)
          dst[colBase + nt * 16] = wgt * (acc[mt][nt][r] + bias[nt]);
      }
    }
  }
}

__global__ __launch_bounds__(256) void combine(
    const float4* __restrict__ y0, const float4* __restrict__ y1,
    float4* __restrict__ out)
{
  const size_t i = (size_t)blockIdx.x * 256 + threadIdx.x;
  float4 a = y0[i], b = y1[i];
  float4 o;
  o.x = a.x + b.x; o.y = a.y + b.y; o.z = a.z + b.z; o.w = a.w + b.w;
  out[i] = o;
}

extern "C" void kernel_launch(void* const* d_in, const int* in_sizes, int n_in,
                              void* d_out, int out_size, void* d_ws, size_t ws_size,
                              hipStream_t stream)
{
  const float* x  = (const float*)d_in[0];
  const float* gW = (const float*)d_in[1];
  const float* gb = (const float*)d_in[2];
  const float* eW = (const float*)d_in[3];
  const float* eb = (const float*)d_in[4];
  float* out = (float*)d_out;

  char* p = (char*)d_ws;
  unsigned short* xb = (unsigned short*)p;  p += (size_t)TOK * DIM * 2;       // 16 MB
  unsigned short* Wt = (unsigned short*)p;  p += (size_t)NE * DIM * DIM * 2;  // 16 MB
  float* yslot = (float*)p;                 p += (size_t)2 * TOK * DIM * 4;   // 64 MB
  int* cnt = (int*)p;                       p += 256;
  int* listTok = (int*)p;                   p += (size_t)NE * TOK * 4;
  float* listW = (float*)p;                 p += (size_t)NE * TOK * 4;
  int* tiles = (int*)p;                     p += 4096;

  // eSel/wSel alias the head of yslot: consumed by scatter_kernel BEFORE
  // moe_gemm overwrites yslot (stream-ordered). Saves 128 KB of ws.
  int*   eSel = (int*)yslot;                  // TOK*2 ints = 64 KB
  float* wSel = (float*)(yslot + TOK * 2);    // TOK*2 floats = 64 KB

  zero_cnt<<<1, 64, 0, stream>>>(cnt);
  gate_kernel<<<TOK / 4, 256, 0, stream>>>(x, gW, gb, xb, eSel, wSel);
  scatter_kernel<<<TOK / 256, 256, 0, stream>>>(eSel, wSel, cnt, listTok, listW);
  transpose_w<<<dim3(32, 32, 8), 256, 0, stream>>>(eW, Wt);
  build_desc<<<1, 64, 0, stream>>>(cnt, tiles);
  moe_gemm<<<136 * 8, 256, 0, stream>>>(xb, Wt, eb, tiles, listTok, listW, yslot);
  combine<<<TOK * DIM / 4 / 256, 256, 0, stream>>>(
      (const float4*)yslot, (const float4*)yslot + (size_t)TOK * DIM / 4, (float4*)out);
}